// Round 1
// baseline (180.006 us; speedup 1.0000x reference)
//
#include <hip/hip_runtime.h>
#include <math.h>

#define BB 64
#define II 1024
#define HH 1024

// ws layout (floats)
#define WS_I     0
#define WS_F     64
#define WS_INVN  128
#define WS_DENOM 192
#define WS_O     256
#define WS_K     (256 + 65536)
#define WS_V     (256 + 2*65536)
#define WS_Q     (256 + 3*65536)

// ---------------- kernel 1: per-batch gates + input norm ----------------
// grid = 64 blocks, block = 64 threads (one wave per batch)
__global__ __launch_bounds__(64) void k_gates(const float* __restrict__ input,
                                              const float* __restrict__ if_w,
                                              const float* __restrict__ if_b,
                                              float* __restrict__ ws) {
    int b = blockIdx.x;
    int lane = threadIdx.x;
    const float4* x4 = (const float4*)(input + (size_t)b * II);
    const float4* w0 = (const float4*)(if_w);
    const float4* w1 = (const float4*)(if_w + II);
    float d0 = 0.f, d1 = 0.f, ss = 0.f;
#pragma unroll
    for (int j = 0; j < 4; ++j) {
        int idx = lane + j * 64;
        float4 xv = x4[idx];
        float4 a = w0[idx];
        float4 c = w1[idx];
        d0 += xv.x*a.x + xv.y*a.y + xv.z*a.z + xv.w*a.w;
        d1 += xv.x*c.x + xv.y*c.y + xv.z*c.z + xv.w*c.w;
        ss += xv.x*xv.x + xv.y*xv.y + xv.z*xv.z + xv.w*xv.w;
    }
#pragma unroll
    for (int off = 32; off > 0; off >>= 1) {
        d0 += __shfl_xor(d0, off);
        d1 += __shfl_xor(d1, off);
        ss += __shfl_xor(ss, off);
    }
    if (lane == 0) {
        ws[WS_I + b]    = expf(d0 + if_b[0]);
        ws[WS_F + b]    = expf(d1 + if_b[1]);
        ws[WS_INVN + b] = 1.0f / sqrtf(ss);
    }
}

// ---------------- kernel 2: o / k / v / q projections (+ n update) ----------------
// one wave per (batch, out-row); rows 0..1023 -> o, 1024..2047 -> k, 2048..3071 -> v, 3072..4095 -> q
// grid = 64*4096/4 = 65536 blocks of 256 threads (4 waves)
__global__ __launch_bounds__(256) void k_proj(const float* __restrict__ input,
                                              const float* __restrict__ o_w,
                                              const float* __restrict__ kvq_w,
                                              const float* __restrict__ o_b,
                                              const float* __restrict__ kvq_b,
                                              const float* __restrict__ prev_n,
                                              float* __restrict__ ws,
                                              float* __restrict__ n_out) {
    int wave = threadIdx.x >> 6, lane = threadIdx.x & 63;
    int gw = blockIdx.x * 4 + wave;          // [0, 64*4096)
    int b = gw >> 12;
    int r = gw & 4095;
    const float4* x4 = (const float4*)(input + (size_t)b * II);
    const float4* w4 = (r < HH) ? (const float4*)(o_w + (size_t)r * II)
                                : (const float4*)(kvq_w + (size_t)(r - HH) * II);
    float d = 0.f;
#pragma unroll
    for (int j = 0; j < 4; ++j) {
        int idx = lane + j * 64;
        float4 xv = x4[idx], wv = w4[idx];
        d += xv.x*wv.x + xv.y*wv.y + xv.z*wv.z + xv.w*wv.w;
    }
#pragma unroll
    for (int off = 32; off > 0; off >>= 1) d += __shfl_xor(d, off);
    if (lane == 0) {
        if (r < HH) {
            ws[WS_O + b * HH + r] = 1.0f / (1.0f + expf(-(d + o_b[r])));
        } else {
            int wk = r - HH;
            int which = wk >> 10;
            int hh = wk & 1023;
            float dn = d * ws[WS_INVN + b];
            if (which == 0) {
                float kv = dn * 0.03125f + kvq_b[hh];     // 1/sqrt(1024) = 0.03125
                ws[WS_K + b * HH + hh] = kv;
                n_out[b * HH + hh] = ws[WS_F + b] * prev_n[b * HH + hh] + ws[WS_I + b] * kv;
            } else if (which == 1) {
                ws[WS_V + b * HH + hh] = dn + kvq_b[HH + hh];
            } else {
                ws[WS_Q + b * HH + hh] = dn + kvq_b[2 * HH + hh];
            }
        }
    }
}

// ---------------- kernel 3: denom = max(|n.q|, 1) per batch ----------------
__global__ __launch_bounds__(256) void k_denom(const float* __restrict__ n_out,
                                               float* __restrict__ ws) {
    int b = blockIdx.x;
    int t = threadIdx.x;
    int wave = t >> 6, lane = t & 63;
    const float* nb = n_out + (size_t)b * HH;
    const float* qb = ws + WS_Q + (size_t)b * HH;
    float s = 0.f;
    for (int idx = t; idx < HH; idx += 256) s += nb[idx] * qb[idx];
#pragma unroll
    for (int off = 32; off > 0; off >>= 1) s += __shfl_xor(s, off);
    __shared__ float red[4];
    if (lane == 0) red[wave] = s;
    __syncthreads();
    if (t == 0) {
        float tot = red[0] + red[1] + red[2] + red[3];
        ws[WS_DENOM + b] = fmaxf(fabsf(tot), 1.0f);
    }
}

// ---------------- kernel 4: c update + fused readout h ----------------
// one wave per c-row (4 KB): c_new = f*prev_c + (i*v_r)*k, h_r = o_r * (c_new . q)/denom
// grid = 65536/4 = 16384 blocks of 256 threads
__global__ __launch_bounds__(256) void k_cup(const float* __restrict__ prev_c,
                                             const float* __restrict__ ws,
                                             float* __restrict__ c_out,
                                             float* __restrict__ h_out) {
    int wave = threadIdx.x >> 6, lane = threadIdx.x & 63;
    int gw = blockIdx.x * 4 + wave;          // row id in [0, 65536) = b*1024 + r
    int b = gw >> 10;
    float fb = ws[WS_F + b], ib = ws[WS_I + b];
    float iv = ib * ws[WS_V + gw];
    const float4* pc = (const float4*)(prev_c + ((size_t)gw << 10));
    float4*       co = (float4*)(c_out + ((size_t)gw << 10));
    const float4* k4 = (const float4*)(ws + WS_K + (size_t)b * HH);
    const float4* q4 = (const float4*)(ws + WS_Q + (size_t)b * HH);
    float s = 0.f;
#pragma unroll
    for (int j = 0; j < 4; ++j) {
        int idx = lane + j * 64;
        float4 p = pc[idx], kv = k4[idx], qv = q4[idx];
        float4 c;
        c.x = fb * p.x + iv * kv.x;
        c.y = fb * p.y + iv * kv.y;
        c.z = fb * p.z + iv * kv.z;
        c.w = fb * p.w + iv * kv.w;
        co[idx] = c;
        s += c.x*qv.x + c.y*qv.y + c.z*qv.z + c.w*qv.w;
    }
#pragma unroll
    for (int off = 32; off > 0; off >>= 1) s += __shfl_xor(s, off);
    if (lane == 0) h_out[gw] = ws[WS_O + gw] * s / ws[WS_DENOM + b];
}

extern "C" void kernel_launch(void* const* d_in, const int* in_sizes, int n_in,
                              void* d_out, int out_size, void* d_ws, size_t ws_size,
                              hipStream_t stream) {
    const float* input  = (const float*)d_in[0];
    // d_in[1] = prev_h (unused by the math)
    const float* prev_c = (const float*)d_in[2];
    const float* prev_n = (const float*)d_in[3];
    const float* if_w   = (const float*)d_in[4];
    const float* o_w    = (const float*)d_in[5];
    const float* kvq_w  = (const float*)d_in[6];
    const float* if_b   = (const float*)d_in[7];
    const float* o_b    = (const float*)d_in[8];
    const float* kvq_b  = (const float*)d_in[9];

    float* out   = (float*)d_out;
    float* h_out = out;                          // [B,H]
    float* c_out = out + 65536;                  // [B,H,H]
    float* n_out = out + 65536 + 67108864;       // [B,H]
    float* ws    = (float*)d_ws;

    k_gates<<<BB, 64, 0, stream>>>(input, if_w, if_b, ws);
    k_proj <<<65536, 256, 0, stream>>>(input, o_w, kvq_w, o_b, kvq_b, prev_n, ws, n_out);
    k_denom<<<BB, 256, 0, stream>>>(n_out, ws);
    k_cup  <<<16384, 256, 0, stream>>>(prev_c, ws, c_out, h_out);
}

// Round 3
// 146.891 us; speedup vs baseline: 1.2254x; 1.2254x over previous
//
#include <hip/hip_runtime.h>
#include <math.h>

#define BB 64
#define II 1024
#define HH 1024

typedef float f4 __attribute__((ext_vector_type(4)));

// ws layout (floats)
#define WS_I     0
#define WS_F     64
#define WS_INVN  128
#define WS_DENOM 192
#define WS_O     256
#define WS_K     (256 + 65536)
#define WS_V     (256 + 2*65536)
#define WS_Q     (256 + 3*65536)

// ---------------- kernel 1: per-batch gates + input norm ----------------
// grid = 64 blocks, block = 64 threads (one wave per batch)
__global__ __launch_bounds__(64) void k_gates(const float* __restrict__ input,
                                              const float* __restrict__ if_w,
                                              const float* __restrict__ if_b,
                                              float* __restrict__ ws) {
    int b = blockIdx.x;
    int lane = threadIdx.x;
    const float4* x4 = (const float4*)(input + (size_t)b * II);
    const float4* w0 = (const float4*)(if_w);
    const float4* w1 = (const float4*)(if_w + II);
    float d0 = 0.f, d1 = 0.f, ss = 0.f;
#pragma unroll
    for (int j = 0; j < 4; ++j) {
        int idx = lane + j * 64;
        float4 xv = x4[idx];
        float4 a = w0[idx];
        float4 c = w1[idx];
        d0 += xv.x*a.x + xv.y*a.y + xv.z*a.z + xv.w*a.w;
        d1 += xv.x*c.x + xv.y*c.y + xv.z*c.z + xv.w*c.w;
        ss += xv.x*xv.x + xv.y*xv.y + xv.z*xv.z + xv.w*xv.w;
    }
#pragma unroll
    for (int off = 32; off > 0; off >>= 1) {
        d0 += __shfl_xor(d0, off);
        d1 += __shfl_xor(d1, off);
        ss += __shfl_xor(ss, off);
    }
    if (lane == 0) {
        ws[WS_I + b]    = expf(d0 + if_b[0]);
        ws[WS_F + b]    = expf(d1 + if_b[1]);
        ws[WS_INVN + b] = 1.0f / sqrtf(ss);
    }
}

// ---------------- kernel 2: blocked o/k/v/q projections (+ n update) ----------------
// Weights read EXACTLY ONCE. Block = 512 threads (8 waves) owns 16 rows.
// lane = batch (64 lanes = 64 batches). X staged in LDS in two 128 KB k-halves,
// quad-XOR swizzled for conflict-free ds_read_b128. Each wave: 2 rows, full dot
// per lane (no cross-lane reduction needed).
__global__ __launch_bounds__(512) void k_proj(const float* __restrict__ input,
                                              const float* __restrict__ o_w,
                                              const float* __restrict__ kvq_w,
                                              const float* __restrict__ o_b,
                                              const float* __restrict__ kvq_b,
                                              const float* __restrict__ prev_n,
                                              float* __restrict__ ws,
                                              float* __restrict__ n_out) {
    __shared__ float xl[64 * 512];          // 128 KB
    float4* xl4 = (float4*)xl;
    const float4* in4 = (const float4*)input;

    int t = threadIdx.x;
    int wave = t >> 6, lane = t & 63;
    int gr0 = blockIdx.x * 16 + wave * 2;   // rows gr0, gr0+1 (same segment: blocks 16-aligned)
    const float* wb0 = (gr0 < HH) ? (o_w + (size_t)gr0 * II)
                                  : (kvq_w + (size_t)(gr0 - HH) * II);
    const float* wb1 = wb0 + II;

    float acc0 = 0.f, acc1 = 0.f;
    int sw = lane & 7;

    for (int h = 0; h < 2; ++h) {
        if (h) __syncthreads();             // all waves done reading half 0
        // stage X[64][512] (k-half h) into LDS, quad-swizzled
#pragma unroll
        for (int j = 0; j < 16; ++j) {
            int e4 = t + j * 512;           // float4 index within the 8192-f4 chunk
            int b  = e4 >> 7;               // 128 f4 per batch row
            int kq = e4 & 127;              // k-quad within half
            float4 v = in4[b * 256 + h * 128 + kq];
            xl4[b * 128 + (kq ^ (b & 7))] = v;
        }
        __syncthreads();

        const float4* w40 = (const float4*)(wb0 + h * 512);
        const float4* w41 = (const float4*)(wb1 + h * 512);
        const float4* xb  = xl4 + lane * 128;
#pragma unroll 8
        for (int q = 0; q < 128; ++q) {
            float4 xv = xb[q ^ sw];
            float4 w0 = w40[q];
            float4 w1 = w41[q];
            acc0 += w0.x*xv.x + w0.y*xv.y + w0.z*xv.z + w0.w*xv.w;
            acc1 += w1.x*xv.x + w1.y*xv.y + w1.z*xv.z + w1.w*xv.w;
        }
    }

    // epilogue: lane = batch b, two rows
    float invn = ws[WS_INVN + lane];
    float fb   = ws[WS_F + lane];
    float ib   = ws[WS_I + lane];
#pragma unroll
    for (int r = 0; r < 2; ++r) {
        int gr = gr0 + r;
        float d = r ? acc1 : acc0;
        if (gr < HH) {
            ws[WS_O + lane * HH + gr] = 1.0f / (1.0f + expf(-(d + o_b[gr])));
        } else {
            int wk = gr - HH;
            int which = wk >> 10;
            int hh = wk & 1023;
            float dn = d * invn;
            if (which == 0) {
                float kv = dn * 0.03125f + kvq_b[hh];      // 1/sqrt(1024)
                ws[WS_K + lane * HH + hh] = kv;
                n_out[lane * HH + hh] = fb * prev_n[lane * HH + hh] + ib * kv;
            } else if (which == 1) {
                ws[WS_V + lane * HH + hh] = dn + kvq_b[HH + hh];
            } else {
                ws[WS_Q + lane * HH + hh] = dn + kvq_b[2 * HH + hh];
            }
        }
    }
}

// ---------------- kernel 3: denom = max(|n.q|, 1) per batch ----------------
__global__ __launch_bounds__(256) void k_denom(const float* __restrict__ n_out,
                                               float* __restrict__ ws) {
    int b = blockIdx.x;
    int t = threadIdx.x;
    int wave = t >> 6, lane = t & 63;
    const float* nb = n_out + (size_t)b * HH;
    const float* qb = ws + WS_Q + (size_t)b * HH;
    float s = 0.f;
    for (int idx = t; idx < HH; idx += 256) s += nb[idx] * qb[idx];
#pragma unroll
    for (int off = 32; off > 0; off >>= 1) s += __shfl_xor(s, off);
    __shared__ float red[4];
    if (lane == 0) red[wave] = s;
    __syncthreads();
    if (t == 0) {
        float tot = red[0] + red[1] + red[2] + red[3];
        ws[WS_DENOM + b] = fmaxf(fabsf(tot), 1.0f);
    }
}

// ---------------- kernel 4: c update + fused readout h ----------------
// one wave per 4 c-rows (same batch): c_new = f*prev_c + (i*v_r)*k,
// h_r = o_r * (c_new . q)/denom. k/q read once per 4 rows. Nontemporal streams.
// grid = 65536/(4*4) = 4096 blocks of 256 threads
__global__ __launch_bounds__(256) void k_cup(const float* __restrict__ prev_c,
                                             const float* __restrict__ ws,
                                             float* __restrict__ c_out,
                                             float* __restrict__ h_out) {
    int wave = threadIdx.x >> 6, lane = threadIdx.x & 63;
    int g0 = (blockIdx.x * 4 + wave) * 4;    // first of 4 rows, all same batch
    int b = g0 >> 10;
    float fb = ws[WS_F + b], ib = ws[WS_I + b];
    float iv0 = ib * ws[WS_V + g0];
    float iv1 = ib * ws[WS_V + g0 + 1];
    float iv2 = ib * ws[WS_V + g0 + 2];
    float iv3 = ib * ws[WS_V + g0 + 3];
    const f4* pc = (const f4*)(prev_c + ((size_t)g0 << 10));
    f4*       co = (f4*)(c_out + ((size_t)g0 << 10));
    const float4* k4 = (const float4*)(ws + WS_K + (size_t)b * HH);
    const float4* q4 = (const float4*)(ws + WS_Q + (size_t)b * HH);
    float s0 = 0.f, s1 = 0.f, s2 = 0.f, s3 = 0.f;
#pragma unroll
    for (int j = 0; j < 4; ++j) {
        int idx = lane + j * 64;
        float4 kv = k4[idx], qv = q4[idx];
        f4 p, c;
        p = __builtin_nontemporal_load(&pc[idx]);
        c.x = fb*p.x + iv0*kv.x; c.y = fb*p.y + iv0*kv.y;
        c.z = fb*p.z + iv0*kv.z; c.w = fb*p.w + iv0*kv.w;
        __builtin_nontemporal_store(c, &co[idx]);
        s0 += c.x*qv.x + c.y*qv.y + c.z*qv.z + c.w*qv.w;

        p = __builtin_nontemporal_load(&pc[idx + 256]);
        c.x = fb*p.x + iv1*kv.x; c.y = fb*p.y + iv1*kv.y;
        c.z = fb*p.z + iv1*kv.z; c.w = fb*p.w + iv1*kv.w;
        __builtin_nontemporal_store(c, &co[idx + 256]);
        s1 += c.x*qv.x + c.y*qv.y + c.z*qv.z + c.w*qv.w;

        p = __builtin_nontemporal_load(&pc[idx + 512]);
        c.x = fb*p.x + iv2*kv.x; c.y = fb*p.y + iv2*kv.y;
        c.z = fb*p.z + iv2*kv.z; c.w = fb*p.w + iv2*kv.w;
        __builtin_nontemporal_store(c, &co[idx + 512]);
        s2 += c.x*qv.x + c.y*qv.y + c.z*qv.z + c.w*qv.w;

        p = __builtin_nontemporal_load(&pc[idx + 768]);
        c.x = fb*p.x + iv3*kv.x; c.y = fb*p.y + iv3*kv.y;
        c.z = fb*p.z + iv3*kv.z; c.w = fb*p.w + iv3*kv.w;
        __builtin_nontemporal_store(c, &co[idx + 768]);
        s3 += c.x*qv.x + c.y*qv.y + c.z*qv.z + c.w*qv.w;
    }
#pragma unroll
    for (int off = 32; off > 0; off >>= 1) {
        s0 += __shfl_xor(s0, off);
        s1 += __shfl_xor(s1, off);
        s2 += __shfl_xor(s2, off);
        s3 += __shfl_xor(s3, off);
    }
    if (lane == 0) {
        float inv_d = 1.0f / ws[WS_DENOM + b];
        h_out[g0]     = ws[WS_O + g0]     * s0 * inv_d;
        h_out[g0 + 1] = ws[WS_O + g0 + 1] * s1 * inv_d;
        h_out[g0 + 2] = ws[WS_O + g0 + 2] * s2 * inv_d;
        h_out[g0 + 3] = ws[WS_O + g0 + 3] * s3 * inv_d;
    }
}

extern "C" void kernel_launch(void* const* d_in, const int* in_sizes, int n_in,
                              void* d_out, int out_size, void* d_ws, size_t ws_size,
                              hipStream_t stream) {
    const float* input  = (const float*)d_in[0];
    // d_in[1] = prev_h (unused by the math)
    const float* prev_c = (const float*)d_in[2];
    const float* prev_n = (const float*)d_in[3];
    const float* if_w   = (const float*)d_in[4];
    const float* o_w    = (const float*)d_in[5];
    const float* kvq_w  = (const float*)d_in[6];
    const float* if_b   = (const float*)d_in[7];
    const float* o_b    = (const float*)d_in[8];
    const float* kvq_b  = (const float*)d_in[9];

    float* out   = (float*)d_out;
    float* h_out = out;                          // [B,H]
    float* c_out = out + 65536;                  // [B,H,H]
    float* n_out = out + 65536 + 67108864;       // [B,H]
    float* ws    = (float*)d_ws;

    k_gates<<<BB, 64, 0, stream>>>(input, if_w, if_b, ws);
    k_proj <<<256, 512, 0, stream>>>(input, o_w, kvq_w, o_b, kvq_b, prev_n, ws, n_out);
    k_denom<<<BB, 256, 0, stream>>>(n_out, ws);
    k_cup  <<<4096, 256, 0, stream>>>(prev_c, ws, c_out, h_out);
}